// Round 27
// baseline (113.919 us; speedup 1.0000x reference)
//
#include <hip/hip_runtime.h>
#include <stdint.h>

// FilteredLReLU: up2(17-tap) -> *2 -> lrelu(0.01) -> down2(17-tap), fused.
// R24 wave-shared pk_fma SWAR + 2-deep per-thread prefetch (R26 fixed):
//   - SEPARATE LDS buffers per tile (no A->B slot reuse): kills the
//     compiler-legal write-after-read reorder that corrupted R26
//     (sga[lane] vs sga[lane+1] don't alias thread-locally, so the
//     scheduler may hoist B-writes above A-reads).
//   - wave_barrier() between stage-A writes and stage-B reads (zero-cost
//     compiler fence for the read-after-write direction).
// Both tiles' x loads issued up front (pinned) so tile B's HBM latency
// hides under tile A's ~500-cycle compute.
//
//   ge[m] = lrelu( sum fe[j]*x[m-4+j] ), go[m] = lrelu( sum fo[j]*x[m-3+j] )
//   z[t]  = sum de[j]*ge[t-4+j] + sum dd[j]*go[t-4+j]   (UP gain in fe/fo)

#define T_LEN 32768
#define R_OUT 8
#define HALF  16384            // tile-B offset

typedef __fp16   cvt2 __attribute__((ext_vector_type(2)));  // pkrtz result
typedef _Float16 hpair __attribute__((ext_vector_type(2))); // arithmetic

__device__ __forceinline__ uint32_t pkrtz(float lo, float hi) {
    cvt2 p = __builtin_amdgcn_cvt_pkrtz(lo, hi);
    return __builtin_bit_cast(uint32_t, p);
}
__device__ __forceinline__ hpair h2(uint32_t u) {
    return __builtin_bit_cast(hpair, u);
}
__device__ __forceinline__ uint32_t u32(hpair h) {
    return __builtin_bit_cast(uint32_t, h);
}
__device__ __forceinline__ hpair pk_fma(hpair a, hpair b, hpair c) {
    return __builtin_elementwise_fma(a, b, c);
}
__device__ __forceinline__ hpair pk_lrelu(hpair v, hpair c01) {
    return __builtin_elementwise_max(v, v * c01);
}

// ---- setup: broadcast tap pairs once into ws[0..33] ----
// ws[0..8]=feB, ws[9..16]=foB, ws[17..25]=deB, ws[26..33]=ddB
__global__ void pack_taps(const float* __restrict__ up,
                          const float* __restrict__ dn,
                          uint32_t* __restrict__ ws) {
    if (threadIdx.x == 0 && blockIdx.x == 0) {
        #pragma unroll
        for (int j = 0; j < 9; ++j) {
            float fe = 2.0f * up[2*j];
            float de = dn[2*j];
            ws[j]      = pkrtz(fe, fe);
            ws[17 + j] = pkrtz(de, de);
        }
        #pragma unroll
        for (int j = 0; j < 8; ++j) {
            float fo = 2.0f * up[2*j+1];
            float dd = dn[2*j+1];
            ws[9 + j]  = pkrtz(fo, fo);
            ws[26 + j] = pkrtz(dd, dd);
        }
    }
}

// compute 4 (ga, go) pairs for output base tb from xv[16] = x[tb-8 .. tb+7]
__device__ __forceinline__ void pairs4(
    const float* xv, const hpair* feB, const hpair* foB, hpair c01,
    uint32_t* ga, uint32_t* go)
{
    uint32_t xau[8], xsu[7];
    #pragma unroll
    for (int k = 0; k < 8; ++k) xau[k] = pkrtz(xv[2*k], xv[2*k+1]);
    #pragma unroll
    for (int k = 0; k < 7; ++k)
        xsu[k] = (xau[k] >> 16) | (xau[k+1] << 16);   // v_alignbit_b32

    #pragma unroll
    for (int q = 0; q < 4; ++q) {
        hpair s = feB[0] * h2(xau[q]);
        #pragma unroll
        for (int a = 1; a < 5; ++a) s = pk_fma(feB[2*a], h2(xau[q+a]), s);
        #pragma unroll
        for (int a = 0; a < 4; ++a) s = pk_fma(feB[2*a+1], h2(xsu[q+a]), s);
        ga[q] = u32(pk_lrelu(s, c01));

        hpair r = foB[0] * h2(xsu[q]);
        #pragma unroll
        for (int a = 1; a < 4; ++a) r = pk_fma(foB[2*a], h2(xsu[q+a]), r);
        #pragma unroll
        for (int a = 0; a < 4; ++a) r = pk_fma(foB[2*a+1], h2(xau[q+a+1]), r);
        go[q] = u32(pk_lrelu(r, c01));
    }
}

// full tile: own pairs -> LDS[TI], distributed halo, fence, scatter, store
#define PROCESS_TILE(TI, XV, TT)                                             \
{                                                                            \
    uint32_t ga[4], go[4];                                                   \
    pairs4(XV, feB, foB, c01, ga, go);                                       \
    if ((TT) == 0) { ga[0]=0u; go[0]=0u; ga[1]=0u; go[1]=0u; }               \
    *reinterpret_cast<uint4*>(&sga[TI][wv][lane][0]) =                       \
        make_uint4(ga[0], ga[1], ga[2], ga[3]);                              \
    *reinterpret_cast<uint4*>(&sgb[TI][wv][lane][0]) =                       \
        make_uint4(go[0], go[1], go[2], go[3]);                              \
    if (lane >= 60) {                                                        \
        const int q  = lane - 60;                                            \
        const int tx = ((TT) - lane * R_OUT) + 512;                          \
        float xw[12];                                                        \
        if (tx + 2*q + 3 < T_LEN) {                                          \
            const float2* xp2 =                                              \
                reinterpret_cast<const float2*>(xrow + tx - 8 + 2*q);        \
            _Pragma("unroll")                                                \
            for (int k = 0; k < 6; ++k) {                                    \
                float2 v = xp2[k];                                           \
                xw[2*k] = v.x; xw[2*k+1] = v.y;                              \
            }                                                                \
        } else {                                                             \
            _Pragma("unroll")                                                \
            for (int i = 0; i < 12; ++i) {                                   \
                int g = tx - 8 + 2*q + i;                                    \
                xw[i] = (g < T_LEN) ? xrow[g] : 0.0f;                        \
            }                                                                \
        }                                                                    \
        uint32_t hau[5], hsu[4];                                             \
        _Pragma("unroll")                                                    \
        for (int k = 0; k < 5; ++k) hau[k] = pkrtz(xw[2*k], xw[2*k+1]);      \
        _Pragma("unroll")                                                    \
        for (int k = 0; k < 4; ++k)                                          \
            hsu[k] = (hau[k] >> 16) | (hau[k+1] << 16);                      \
        hpair s = feB[0] * h2(hau[0]);                                       \
        _Pragma("unroll")                                                    \
        for (int a = 1; a < 5; ++a) s = pk_fma(feB[2*a], h2(hau[a]), s);     \
        _Pragma("unroll")                                                    \
        for (int a = 0; a < 4; ++a) s = pk_fma(feB[2*a+1], h2(hsu[a]), s);   \
        uint32_t ha = u32(pk_lrelu(s, c01));                                 \
        hpair r = foB[0] * h2(hsu[0]);                                       \
        _Pragma("unroll")                                                    \
        for (int a = 1; a < 4; ++a) r = pk_fma(foB[2*a], h2(hsu[a]), r);     \
        _Pragma("unroll")                                                    \
        for (int a = 0; a < 4; ++a) r = pk_fma(foB[2*a+1], h2(hau[a+1]), r); \
        uint32_t hb = u32(pk_lrelu(r, c01));                                 \
        const int m0 = tx - 4 + 2*q;                                         \
        const uint32_t msk = ((m0   < T_LEN) ? 0x0000FFFFu : 0u)             \
                           | ((m0+1 < T_LEN) ? 0xFFFF0000u : 0u);            \
        sga[TI][wv][64][q] = ha & msk;                                       \
        sgb[TI][wv][64][q] = hb & msk;                                       \
    }                                                                        \
    __builtin_amdgcn_wave_barrier();  /* fence: writes before reads */       \
    {                                                                        \
        uint4 GN = *reinterpret_cast<const uint4*>(&sga[TI][wv][lane+1][0]); \
        uint4 ON = *reinterpret_cast<const uint4*>(&sgb[TI][wv][lane+1][0]); \
        uint32_t gaF[8] = {ga[0],ga[1],ga[2],ga[3],GN.x,GN.y,GN.z,GN.w};     \
        uint32_t goF[8] = {go[0],go[1],go[2],go[3],ON.x,ON.y,ON.z,ON.w};     \
        uint32_t gsh[7], gosh[7];                                            \
        _Pragma("unroll")                                                    \
        for (int k = 0; k < 7; ++k) {                                        \
            gsh[k]  = (gaF[k] >> 16) | (gaF[k+1] << 16);                     \
            gosh[k] = (goF[k] >> 16) | (goF[k+1] << 16);                     \
        }                                                                    \
        hpair zp[4];                                                         \
        _Pragma("unroll")                                                    \
        for (int p = 0; p < 4; ++p) {                                        \
            hpair s = deB[0] * h2(gaF[p]);                                   \
            _Pragma("unroll")                                                \
            for (int a = 1; a < 5; ++a) s = pk_fma(deB[2*a], h2(gaF[p+a]), s); \
            _Pragma("unroll")                                                \
            for (int a = 0; a < 4; ++a) s = pk_fma(deB[2*a+1], h2(gsh[p+a]), s); \
            _Pragma("unroll")                                                \
            for (int a = 0; a < 4; ++a) s = pk_fma(ddB[2*a], h2(goF[p+a]), s); \
            _Pragma("unroll")                                                \
            for (int a = 0; a < 4; ++a) s = pk_fma(ddB[2*a+1], h2(gosh[p+a]), s); \
            zp[p] = s;                                                       \
        }                                                                    \
        float4* op = reinterpret_cast<float4*>(orow + (TT));                 \
        op[0] = make_float4((float)zp[0][0], (float)zp[0][1],                \
                            (float)zp[1][0], (float)zp[1][1]);               \
        op[1] = make_float4((float)zp[2][0], (float)zp[2][1],                \
                            (float)zp[3][0], (float)zp[3][1]);               \
    }                                                                        \
}

__global__ void flrelu_pf2b(
    const float* __restrict__ x,
    const uint32_t* __restrict__ tw,
    float* __restrict__ out)
{
    // separate buffers per tile: no write-after-read hazard across tiles
    __shared__ __align__(16) uint32_t sga[2][4][66][4];
    __shared__ __align__(16) uint32_t sgb[2][4][66][4];

    const int tid  = threadIdx.x;
    const int lane = tid & 63;
    const int wv   = tid >> 6;
    const int gid  = blockIdx.x * 256 + tid;
    const int row  = gid >> 11;                 // 2048 threads per row
    const int t    = (gid & 2047) * R_OUT;      // tile A base; tile B = t+HALF
    const float* __restrict__ xrow = x + (size_t)row * T_LEN;
    float* __restrict__ orow       = out + (size_t)row * T_LEN;

    // taps: uniform pointer + const idx -> s_loads
    hpair feB[9], foB[8], deB[9], ddB[8];
    #pragma unroll
    for (int j = 0; j < 9; ++j) { feB[j] = h2(tw[j]); deB[j] = h2(tw[17+j]); }
    #pragma unroll
    for (int j = 0; j < 8; ++j) { foB[j] = h2(tw[9+j]); ddB[j] = h2(tw[26+j]); }
    const hpair c01 = h2(pkrtz(0.01f, 0.01f));

    // ---- issue BOTH tiles' loads up front ----
    float xvA[16], xvB[16];
    if (t >= 8) {
        const float4* xp = reinterpret_cast<const float4*>(xrow + t - 8);
        float4 v0 = xp[0], v1 = xp[1], v2 = xp[2], v3 = xp[3];
        xvA[0]=v0.x; xvA[1]=v0.y; xvA[2]=v0.z; xvA[3]=v0.w;
        xvA[4]=v1.x; xvA[5]=v1.y; xvA[6]=v1.z; xvA[7]=v1.w;
        xvA[8]=v2.x; xvA[9]=v2.y; xvA[10]=v2.z; xvA[11]=v2.w;
        xvA[12]=v3.x; xvA[13]=v3.y; xvA[14]=v3.z; xvA[15]=v3.w;
    } else {
        #pragma unroll
        for (int i = 0; i < 16; ++i) {
            int g = t - 8 + i;
            xvA[i] = (g >= 0) ? xrow[g] : 0.0f;
        }
    }
    {
        // tile B is always interior (t+HALF-8 >= 16376, t+HALF+7 <= 32767)
        const float4* xp = reinterpret_cast<const float4*>(xrow + t + HALF - 8);
        float4 v0 = xp[0], v1 = xp[1], v2 = xp[2], v3 = xp[3];
        xvB[0]=v0.x; xvB[1]=v0.y; xvB[2]=v0.z; xvB[3]=v0.w;
        xvB[4]=v1.x; xvB[5]=v1.y; xvB[6]=v1.z; xvB[7]=v1.w;
        xvB[8]=v2.x; xvB[9]=v2.y; xvB[10]=v2.z; xvB[11]=v2.w;
        xvB[12]=v3.x; xvB[13]=v3.y; xvB[14]=v3.z; xvB[15]=v3.w;
    }
    #pragma unroll
    for (int i = 0; i < 16; ++i) {
        asm volatile("" : "+v"(xvB[i]));   // keep B's loads issued & live
    }

    // ---- tile A then tile B (B's data already in registers) ----
    PROCESS_TILE(0, xvA, t)
    PROCESS_TILE(1, xvB, t + HALF)
}

extern "C" void kernel_launch(void* const* d_in, const int* in_sizes, int n_in,
                              void* d_out, int out_size, void* d_ws, size_t ws_size,
                              hipStream_t stream) {
    const float* x  = (const float*)d_in[0];
    const float* up = (const float*)d_in[1];
    const float* dn = (const float*)d_in[2];
    float* out      = (float*)d_out;
    uint32_t* ws    = (uint32_t*)d_ws;

    pack_taps<<<1, 64, 0, stream>>>(up, dn, ws);

    const int rows    = in_sizes[0] / T_LEN;         // 2048
    const int threads = rows * (T_LEN / (2 * R_OUT));// 4.19M
    flrelu_pf2b<<<threads / 256, 256, 0, stream>>>(x, ws, out);
}